// Round 1
// 304.699 us; speedup vs baseline: 1.1077x; 1.1077x over previous
//
#include <hip/hip_runtime.h>
#include <cstddef>
#include <cstdint>

// ---------------------------------------------------------------------------
// attention_net_noc: pointer-network decode step.
// R4: (a) adjacent row-pair (2t,2t+1) + feature-pair-interleaved E-cache tile
//     [blk][8][512*float4] -> all cache stores/loads are lane-contiguous
//     16B/lane float4 with zero repack movs (was stride-64B 16B/lane + ~96
//     movs/thread); (b) 5-instr tanh via v_exp/v_rcp builtins (was 7);
//     (c) k_init fused into k_emb_g1 prologue (one fewer launch);
//     (d) k_combine_g reduction via block_sum17 (was 34 serial block_sums).
// ---------------------------------------------------------------------------

constexpr int NJ = 1000000;
constexpr int NM = 500000;
constexpr float NEGV = -1e8f;

constexpr int BLK = 256;
constexpr int ROWS_PER_BLK = 512;            // 2 adjacent rows per thread
constexpr int GB_J2 = (NJ + ROWS_PER_BLK - 1) / ROWS_PER_BLK;  // 1954
constexpr int GB_M2 = (NM + ROWS_PER_BLK - 1) / ROWS_PER_BLK;  // 977
constexpr int GB_TOT2 = GB_J2 + GB_M2;                          // 2931
constexpr int EBLK = ROWS_PER_BLK * 16;                         // 8192 floats/tile

// ---- workspace layout (float offsets from start of d_ws) ----
constexpr int S_QKJA = 0;    // 16: ja_Wq@g1 + ja_bq
constexpr int S_QK2J = 16;   // 16: aj_Wq@e_js + aj_bq
constexpr int S_QK2M = 32;   // 16: am_Wq@e_js + am_bq
constexpr int S_EJS  = 48;   // 16: E_j[sel_j]
constexpr int S_QKMA = 64;   // 16: ma_Wq@g2 + ma_bq
constexpr int S_LOGPJ = 80;
constexpr int S_SELJ  = 81;  // stored as float (exact, < 2^24)
constexpr int P1J = 128;                       // GB_J2*17 glimpse partials (l, s[16])
constexpr int P1M = P1J + GB_J2 * 17;          // GB_M2*17
constexpr int P2V = P1M + GB_M2 * 17;          // GB_J2 argmax vals (mlogits reuses)
constexpr int P2I = P2V + GB_J2;
constexpr int P2L = P2I + GB_J2;
constexpr size_t E_OFF = 65536;                // float offset of E_j cache
static_assert(P2L + GB_J2 <= (int)E_OFF, "partials overflow into E cache");

typedef float v2f __attribute__((ext_vector_type(2)));

struct Params {
    const float *jobs, *machines;
    const int *mask;
    const float *jW1, *jb1, *jW2, *jb2;
    const float *mW1, *mb1, *mW2, *mb2;
    const float *aj_Wq, *aj_bq, *aj_Wr, *aj_V;
    const float *am_Wq, *am_bq, *am_Wr, *am_V;
    const float *ja_Wq, *ja_bq, *ja_Wr, *ja_V;
    const float *ma_Wq, *ma_bq, *ma_Wr, *ma_V;
    const float *g1W, *g1b, *g2W, *g2b, *last_j;
    float *S;        // smalls + partials (in ws)
    float *Ej, *Em;  // embedding cache tiles (in ws; valid only if CACHE)
    float *out;
};

// ---------------------------------------------------------------------------
// device helpers
// ---------------------------------------------------------------------------

// tanh(x) = 1 - 2*rcp(exp2(x*2*log2e)+1). 5 instrs: mul, v_exp, add, v_rcp, fma.
// |x| <= ~3 here; abs err ~2e-7 vs np.tanh (same HW ops as before, fused consts).
__device__ __forceinline__ float fast_tanh(float x) {
    float e = __builtin_amdgcn_exp2f(x * 2.8853900817779268f);  // 2/ln2
    float r = __builtin_amdgcn_rcpf(e + 1.0f);
    return fmaf(-2.0f, r, 1.0f);
}

__device__ __forceinline__ v2f vbc(float a) { v2f r; r.x = a; r.y = a; return r; }

// packed fma: one v_pk_fma_f32 issue slot for two fp32 FMAs (bit-identical)
__device__ __forceinline__ v2f vfma(float w, v2f b, v2f c) {
    return __builtin_elementwise_fma(vbc(w), b, c);
}
__device__ __forceinline__ v2f vfma2(v2f a, v2f b, v2f c) {
    return __builtin_elementwise_fma(a, b, c);
}
__device__ __forceinline__ v2f vtanh(v2f a) {
    v2f r; r.x = fast_tanh(a.x); r.y = fast_tanh(a.y); return r;
}

__device__ __forceinline__ void load16(const float* __restrict__ X, size_t r, float (&x)[16]) {
    const float4* p4 = reinterpret_cast<const float4*>(X) + r * 4;
    float4 a = p4[0], b = p4[1], c = p4[2], d = p4[3];
    x[0]=a.x; x[1]=a.y; x[2]=a.z; x[3]=a.w;
    x[4]=b.x; x[5]=b.y; x[6]=b.z; x[7]=b.w;
    x[8]=c.x; x[9]=c.y; x[10]=c.z; x[11]=c.w;
    x[12]=d.x; x[13]=d.y; x[14]=d.z; x[15]=d.w;
}

// load rows rA, rB and pack feature-wise into v2f lanes (.x=rowA, .y=rowB)
__device__ __forceinline__ void load16_v2(const float* __restrict__ X, size_t rA, size_t rB,
                                          v2f (&x)[16]) {
    float a[16], b[16];
    load16(X, rA, a);
    load16(X, rB, b);
#pragma unroll
    for (int k = 0; k < 16; ++k) { x[k].x = a[k]; x[k].y = b[k]; }
}

// E-cache tile: [8][512 rows as float4 {e[2k](rA,rB), e[2k+1](rA,rB)}]
// thread t owns rows (2t,2t+1): store/load index = kp*256 + t  (16B/lane, contiguous)
__device__ __forceinline__ void ecache_store(float* __restrict__ Eb, int t, const v2f (&e)[16]) {
    float4* p4 = reinterpret_cast<float4*>(Eb);
#pragma unroll
    for (int kp = 0; kp < 8; ++kp)
        p4[kp * 256 + t] = make_float4(e[2*kp].x, e[2*kp].y, e[2*kp+1].x, e[2*kp+1].y);
}
__device__ __forceinline__ void ecache_load(const float* __restrict__ Eb, int t, v2f (&e)[16]) {
    const float4* p4 = reinterpret_cast<const float4*>(Eb);
#pragma unroll
    for (int kp = 0; kp < 8; ++kp) {
        float4 q = p4[kp * 256 + t];
        e[2*kp].x = q.x;   e[2*kp].y = q.y;
        e[2*kp+1].x = q.z; e[2*kp+1].y = q.w;
    }
}

// e = tanh(W2 @ tanh(W1 @ x + b1) + b2) for a packed row-pair
__device__ __forceinline__ void emb16_v2(const v2f (&x)[16],
                                         const float* __restrict__ W1, const float* __restrict__ b1,
                                         const float* __restrict__ W2, const float* __restrict__ b2,
                                         v2f (&e)[16]) {
    v2f h[16];
#pragma unroll
    for (int i = 0; i < 16; ++i) {
        v2f a = vbc(b1[i]);
#pragma unroll
        for (int k = 0; k < 16; ++k) a = vfma(W1[i * 16 + k], x[k], a);
        h[i] = vtanh(a);
    }
#pragma unroll
    for (int i = 0; i < 16; ++i) {
        v2f a = vbc(b2[i]);
#pragma unroll
        for (int k = 0; k < 16; ++k) a = vfma(W2[i * 16 + k], h[k], a);
        e[i] = vtanh(a);
    }
}

// logit = tanh(qk + Wr @ e) . V for a packed row-pair
__device__ __forceinline__ v2f att_logit_v2(const v2f (&e)[16], const float (&qk)[16],
                                            const float* __restrict__ Wr,
                                            const float* __restrict__ V) {
    v2f acc = vbc(0.0f);
#pragma unroll
    for (int i = 0; i < 16; ++i) {
        v2f r = vbc(qk[i]);
#pragma unroll
        for (int k = 0; k < 16; ++k) r = vfma(Wr[i * 16 + k], e[k], r);
        acc = vfma2(vbc(V[i]), vtanh(r), acc);
    }
    return acc;
}

__device__ __forceinline__ float wave_reduce_sum(float v) {
#pragma unroll
    for (int off = 32; off > 0; off >>= 1) v += __shfl_xor(v, off, 64);
    return v;
}

__device__ __forceinline__ void wave_reduce_argmax(float &v, int &idx) {
#pragma unroll
    for (int off = 32; off > 0; off >>= 1) {
        float ov = __shfl_xor(v, off, 64);
        int oi = __shfl_xor(idx, off, 64);
        if (ov > v || (ov == v && oi < idx)) { v = ov; idx = oi; }
    }
}

__device__ __forceinline__ float block_sum(float v) {
    __shared__ float sm[4];
    v = wave_reduce_sum(v);
    __syncthreads();
    if ((threadIdx.x & 63) == 0) sm[threadIdx.x >> 6] = v;
    __syncthreads();
    return sm[0] + sm[1] + sm[2] + sm[3];
}

__device__ __forceinline__ void block_argmax(float &v, int &i) {
    __shared__ float sv[4];
    __shared__ int si[4];
    wave_reduce_argmax(v, i);
    __syncthreads();
    if ((threadIdx.x & 63) == 0) { sv[threadIdx.x >> 6] = v; si[threadIdx.x >> 6] = i; }
    __syncthreads();
    float bv = sv[0]; int bi = si[0];
#pragma unroll
    for (int k = 1; k < 4; ++k)
        if (sv[k] > bv || (sv[k] == bv && si[k] < bi)) { bv = sv[k]; bi = si[k]; }
    v = bv; i = bi;
}

// reduce (l, s[16]) across the block, write 17 floats to dst (global or shared).
// Leading sync protects the static LDS buffer when called twice in one kernel.
__device__ __forceinline__ void block_sum17(float l, float (&s)[16], float* dst) {
    l = wave_reduce_sum(l);
#pragma unroll
    for (int i = 0; i < 16; ++i) s[i] = wave_reduce_sum(s[i]);
    __shared__ float red[4][17];
    int w = threadIdx.x >> 6, ln = threadIdx.x & 63;
    __syncthreads();
    if (ln == 0) {
        red[w][0] = l;
#pragma unroll
        for (int i = 0; i < 16; ++i) red[w][1 + i] = s[i];
    }
    __syncthreads();
    if (threadIdx.x < 17)
        dst[threadIdx.x] = red[0][threadIdx.x] + red[1][threadIdx.x] + red[2][threadIdx.x] + red[3][threadIdx.x];
}

// ---------------------------------------------------------------------------
// K1: embeddings (optionally cached to ws) + glimpse-1 partial sums.
// blocks [0,GB_J2) -> jobs, [GB_J2,GB_TOT2) -> machines. Rows (2t,2t+1).
// qk1 (Wq@last_j+bq) computed per-block in a 16-thread prologue (was k_init).
// ---------------------------------------------------------------------------
template <bool CACHE>
__global__ __launch_bounds__(BLK) void k_emb_g1(Params p) {
    const bool isJob = blockIdx.x < GB_J2;
    const float* X  = isJob ? p.jobs : p.machines;
    const float* W1 = isJob ? p.jW1 : p.mW1;
    const float* b1 = isJob ? p.jb1 : p.mb1;
    const float* W2 = isJob ? p.jW2 : p.mW2;
    const float* b2 = isJob ? p.jb2 : p.mb2;
    const float* Wr = isJob ? p.aj_Wr : p.am_Wr;
    const float* V  = isJob ? p.aj_V  : p.am_V;
    float* E = isJob ? p.Ej : p.Em;
    const int n  = isJob ? NJ : NM;
    const int b0 = isJob ? (int)blockIdx.x : (int)blockIdx.x - GB_J2;

    __shared__ float qks[16];
    if (threadIdx.x < 16) {
        const float* Wq = isJob ? p.aj_Wq : p.am_Wq;
        const float* bq = isJob ? p.aj_bq : p.am_bq;
        const int i = threadIdx.x;
        float a = bq[i];
#pragma unroll
        for (int k = 0; k < 16; ++k) a = fmaf(Wq[i * 16 + k], p.last_j[k], a);
        qks[i] = a;
    }
    __syncthreads();
    float qk[16];
#pragma unroll
    for (int i = 0; i < 16; ++i) qk[i] = qks[i];

    const int r0 = b0 * ROWS_PER_BLK + 2 * (int)threadIdx.x;
    const int r1 = r0 + 1;
    const bool v0 = r0 < n, v1 = r1 < n;
    const size_t a0 = (size_t)(v0 ? r0 : 0);
    const size_t a1 = (size_t)(v1 ? r1 : 0);

    v2f x[16], e[16];
    load16_v2(X, a0, a1, x);
    emb16_v2(x, W1, b1, W2, b2, e);
    if (CACHE) ecache_store(E + (size_t)b0 * EBLK, (int)threadIdx.x, e);
    v2f lg = att_logit_v2(e, qk, Wr, V);
    // |logit| <= sum|V| ~ 0.6 -> exp never overflows; no max-shift needed.
    float pw0 = v0 ? __expf(lg.x) : 0.0f;
    float pw1 = v1 ? __expf(lg.y) : 0.0f;
    float l = pw0 + pw1, s[16];
#pragma unroll
    for (int i = 0; i < 16; ++i) s[i] = fmaf(pw0, e[i].x, pw1 * e[i].y);

    block_sum17(l, s, p.S + (isJob ? P1J : P1M) + (size_t)b0 * 17);
}

// ---------------------------------------------------------------------------
// Combine partials -> g (g1 or g2) -> next-stage qk vector. Single block.
// ---------------------------------------------------------------------------
__global__ __launch_bounds__(BLK) void k_combine_g(Params p, int phase) {
    const float* PJ = p.S + P1J;
    const float* PM = p.S + P1M;
    float lJ = 0.0f, lM = 0.0f, sJ[16], sM[16];
#pragma unroll
    for (int c = 0; c < 16; ++c) { sJ[c] = 0.0f; sM[c] = 0.0f; }
    for (int i = threadIdx.x; i < GB_J2; i += BLK) {
        lJ += PJ[i * 17];
#pragma unroll
        for (int c = 0; c < 16; ++c) sJ[c] += PJ[i * 17 + 1 + c];
    }
    for (int i = threadIdx.x; i < GB_M2; i += BLK) {
        lM += PM[i * 17];
#pragma unroll
        for (int c = 0; c < 16; ++c) sM[c] += PM[i * 17 + 1 + c];
    }
    __shared__ float totJ[17], totM[17];
    block_sum17(lJ, sJ, totJ);
    block_sum17(lM, sM, totM);
    __syncthreads();

    __shared__ float cb[48], gbuf[16];
    if (threadIdx.x < 16) {
        int i = threadIdx.x;
        cb[i]      = phase ? p.S[S_EJS + i] : p.last_j[i];
        cb[16 + i] = totJ[1 + i] / totJ[0];   // softmax-weighted sum / partition
        cb[32 + i] = totM[1 + i] / totM[0];
    }
    __syncthreads();
    const float* gW  = phase ? p.g2W : p.g1W;
    const float* gbv = phase ? p.g2b : p.g1b;
    if (threadIdx.x < 16) {
        int i = threadIdx.x;
        float a = gbv[i];
#pragma unroll
        for (int k = 0; k < 48; ++k) a = fmaf(gW[i * 48 + k], cb[k], a);
        gbuf[i] = fast_tanh(a);
    }
    __syncthreads();
    const float* Wq = phase ? p.ma_Wq : p.ja_Wq;
    const float* bq = phase ? p.ma_bq : p.ja_bq;
    const int off = phase ? S_QKMA : S_QKJA;
    if (threadIdx.x < 16) {
        int i = threadIdx.x;
        float a = bq[i];
#pragma unroll
        for (int k = 0; k < 16; ++k) a = fmaf(Wq[i * 16 + k], gbuf[k], a);
        p.S[off + i] = a;
    }
}

// ---------------------------------------------------------------------------
// K3: job pointer logits -> masked argmax + sum-exp partials. Rows (2t,2t+1).
// ---------------------------------------------------------------------------
template <bool CACHE>
__global__ __launch_bounds__(BLK) void k_jlogits(Params p) {
    float qk[16];
#pragma unroll
    for (int i = 0; i < 16; ++i) qk[i] = p.S[S_QKJA + i];

    const int r0 = blockIdx.x * ROWS_PER_BLK + 2 * (int)threadIdx.x;
    const int r1 = r0 + 1;
    const bool v0 = r0 < NJ, v1 = r1 < NJ;
    const size_t a0 = (size_t)(v0 ? r0 : 0);
    const size_t a1 = (size_t)(v1 ? r1 : 0);

    v2f e[16];
    if (CACHE) {
        ecache_load(p.Ej + (size_t)blockIdx.x * EBLK, (int)threadIdx.x, e);
    } else {
        v2f x[16];
        load16_v2(p.jobs, a0, a1, x);
        emb16_v2(x, p.jW1, p.jb1, p.jW2, p.jb2, e);
    }
    v2f lg = att_logit_v2(e, qk, p.ja_Wr, p.ja_V);
    const bool m0 = v0 && (p.mask[a0] != 0);
    const bool m1 = v1 && (p.mask[a1] != 0);
    float l = (m0 ? __expf(lg.x) : 0.0f) + (m1 ? __expf(lg.y) : 0.0f);
    float am0 = m0 ? lg.x : NEGV - 1.0f;   // invalid rows below masked NEG
    float am1 = m1 ? lg.y : NEGV - 1.0f;
    float best;
    int bi;
    if (am0 >= am1) { best = am0; bi = r0; }
    else            { best = am1; bi = r1; }

    l = wave_reduce_sum(l);
    wave_reduce_argmax(best, bi);
    __shared__ float rl[4], rv[4];
    __shared__ int ri[4];
    int w = threadIdx.x >> 6, ln = threadIdx.x & 63;
    if (ln == 0) { rl[w] = l; rv[w] = best; ri[w] = bi; }
    __syncthreads();
    if (threadIdx.x == 0) {
        float L = rl[0] + rl[1] + rl[2] + rl[3];
        float v = rv[0]; int i = ri[0];
#pragma unroll
        for (int k = 1; k < 4; ++k)
            if (rv[k] > v || (rv[k] == v && ri[k] < i)) { v = rv[k]; i = ri[k]; }
        p.S[P2V + blockIdx.x] = v;
        p.S[P2I + blockIdx.x] = (float)i;   // exact: i < 2^24
        p.S[P2L + blockIdx.x] = L;
    }
}

// ---------------------------------------------------------------------------
// C2: global argmax over job logits; logp_j; e_js = emb(jobs[sel_j]); qk2j/qk2m
// ---------------------------------------------------------------------------
__global__ __launch_bounds__(BLK) void k_combine2(Params p) {
    float v = -3.4e38f; int vi = 0x7fffffff; float l = 0.0f;
    for (int i = threadIdx.x; i < GB_J2; i += BLK) {
        float pv = p.S[P2V + i];
        int pi = (int)p.S[P2I + i];
        if (pv > v || (pv == v && pi < vi)) { v = pv; vi = pi; }
        l += p.S[P2L + i];
    }
    l = block_sum(l);
    block_argmax(v, vi);
    const int sel = vi;

    __shared__ float xb[16], hb[16], eb[16];
    if (threadIdx.x < 16) xb[threadIdx.x] = p.jobs[(size_t)sel * 16 + threadIdx.x];
    __syncthreads();
    if (threadIdx.x < 16) {
        int i = threadIdx.x;
        float a = p.jb1[i];
#pragma unroll
        for (int k = 0; k < 16; ++k) a = fmaf(p.jW1[i * 16 + k], xb[k], a);
        hb[i] = fast_tanh(a);
    }
    __syncthreads();
    if (threadIdx.x < 16) {
        int i = threadIdx.x;
        float a = p.jb2[i];
#pragma unroll
        for (int k = 0; k < 16; ++k) a = fmaf(p.jW2[i * 16 + k], hb[k], a);
        float e = fast_tanh(a);
        eb[i] = e;
        p.S[S_EJS + i] = e;
    }
    __syncthreads();
    if (threadIdx.x < 16) {
        int i = threadIdx.x;
        float a1 = p.aj_bq[i], a2 = p.am_bq[i];
#pragma unroll
        for (int k = 0; k < 16; ++k) {
            a1 = fmaf(p.aj_Wq[i * 16 + k], eb[k], a1);
            a2 = fmaf(p.am_Wq[i * 16 + k], eb[k], a2);
        }
        p.S[S_QK2J + i] = a1;
        p.S[S_QK2M + i] = a2;
    }
    if (threadIdx.x == 0) {
        p.S[S_LOGPJ] = v - logf(l);     // log_softmax at the argmax
        p.S[S_SELJ] = (float)sel;
    }
}

// ---------------------------------------------------------------------------
// K4: glimpse-2 over jobs (aj_*) and machines (am_*), query e_js. Rows (2t,2t+1).
// Writes partials into the (already consumed) P1 buffers.
// ---------------------------------------------------------------------------
template <bool CACHE>
__global__ __launch_bounds__(BLK) void k_glimpse2(Params p) {
    const bool isJob = blockIdx.x < GB_J2;
    const float* Wr = isJob ? p.aj_Wr : p.am_Wr;
    const float* V  = isJob ? p.aj_V  : p.am_V;
    const float* E  = isJob ? p.Ej : p.Em;
    const float* X  = isJob ? p.jobs : p.machines;
    const float* W1 = isJob ? p.jW1 : p.mW1;
    const float* b1 = isJob ? p.jb1 : p.mb1;
    const float* W2 = isJob ? p.jW2 : p.mW2;
    const float* b2 = isJob ? p.jb2 : p.mb2;
    const int n  = isJob ? NJ : NM;
    const int b0 = isJob ? (int)blockIdx.x : (int)blockIdx.x - GB_J2;
    const int qoff = isJob ? S_QK2J : S_QK2M;

    float qk[16];
#pragma unroll
    for (int i = 0; i < 16; ++i) qk[i] = p.S[qoff + i];

    const int r0 = b0 * ROWS_PER_BLK + 2 * (int)threadIdx.x;
    const int r1 = r0 + 1;
    const bool v0 = r0 < n, v1 = r1 < n;
    const size_t a0 = (size_t)(v0 ? r0 : 0);
    const size_t a1 = (size_t)(v1 ? r1 : 0);

    v2f e[16];
    if (CACHE) {
        ecache_load(E + (size_t)b0 * EBLK, (int)threadIdx.x, e);
    } else {
        v2f x[16];
        load16_v2(X, a0, a1, x);
        emb16_v2(x, W1, b1, W2, b2, e);
    }
    v2f lg = att_logit_v2(e, qk, Wr, V);
    float pw0 = v0 ? __expf(lg.x) : 0.0f;
    float pw1 = v1 ? __expf(lg.y) : 0.0f;
    float l = pw0 + pw1, s[16];
#pragma unroll
    for (int i = 0; i < 16; ++i) s[i] = fmaf(pw0, e[i].x, pw1 * e[i].y);

    block_sum17(l, s, p.S + (isJob ? P1J : P1M) + (size_t)b0 * 17);
}

// ---------------------------------------------------------------------------
// K5: machine logits -> argmax + sum-exp partials. Rows (2t,2t+1).
// Writes into the (already consumed) P2 buffers.
// ---------------------------------------------------------------------------
template <bool CACHE>
__global__ __launch_bounds__(BLK) void k_mlogits(Params p) {
    float qk[16];
#pragma unroll
    for (int i = 0; i < 16; ++i) qk[i] = p.S[S_QKMA + i];

    const int r0 = blockIdx.x * ROWS_PER_BLK + 2 * (int)threadIdx.x;
    const int r1 = r0 + 1;
    const bool v0 = r0 < NM, v1 = r1 < NM;
    const size_t a0 = (size_t)(v0 ? r0 : 0);
    const size_t a1 = (size_t)(v1 ? r1 : 0);

    v2f e[16];
    if (CACHE) {
        ecache_load(p.Em + (size_t)blockIdx.x * EBLK, (int)threadIdx.x, e);
    } else {
        v2f x[16];
        load16_v2(p.machines, a0, a1, x);
        emb16_v2(x, p.mW1, p.mb1, p.mW2, p.mb2, e);
    }
    v2f lg = att_logit_v2(e, qk, p.ma_Wr, p.ma_V);
    float l = (v0 ? __expf(lg.x) : 0.0f) + (v1 ? __expf(lg.y) : 0.0f);
    float am0 = v0 ? lg.x : -3.4e38f;
    float am1 = v1 ? lg.y : -3.4e38f;
    float best;
    int bi;
    if (am0 >= am1) { best = am0; bi = r0; }
    else            { best = am1; bi = r1; }

    l = wave_reduce_sum(l);
    wave_reduce_argmax(best, bi);
    __shared__ float rl[4], rv[4];
    __shared__ int ri[4];
    int w = threadIdx.x >> 6, ln = threadIdx.x & 63;
    if (ln == 0) { rl[w] = l; rv[w] = best; ri[w] = bi; }
    __syncthreads();
    if (threadIdx.x == 0) {
        float L = rl[0] + rl[1] + rl[2] + rl[3];
        float v = rv[0]; int i = ri[0];
#pragma unroll
        for (int k = 1; k < 4; ++k)
            if (rv[k] > v || (rv[k] == v && ri[k] < i)) { v = rv[k]; i = ri[k]; }
        p.S[P2V + blockIdx.x] = v;
        p.S[P2I + blockIdx.x] = (float)i;
        p.S[P2L + blockIdx.x] = L;
    }
}

// ---------------------------------------------------------------------------
// C4: final combine -> outputs [sel_j, sel_m, logpas] as float32
// ---------------------------------------------------------------------------
__global__ __launch_bounds__(BLK) void k_combine4(Params p) {
    float v = -3.4e38f; int vi = 0x7fffffff; float l = 0.0f;
    for (int i = threadIdx.x; i < GB_M2; i += BLK) {
        float pv = p.S[P2V + i];
        int pi = (int)p.S[P2I + i];
        if (pv > v || (pv == v && pi < vi)) { v = pv; vi = pi; }
        l += p.S[P2L + i];
    }
    l = block_sum(l);
    block_argmax(v, vi);
    if (threadIdx.x == 0) {
        p.out[0] = p.S[S_SELJ];
        p.out[1] = (float)vi;
        p.out[2] = p.S[S_LOGPJ] + (v - logf(l));
    }
}

// ---------------------------------------------------------------------------
extern "C" void kernel_launch(void* const* d_in, const int* in_sizes, int n_in,
                              void* d_out, int out_size, void* d_ws, size_t ws_size,
                              hipStream_t stream) {
    Params p;
    p.jobs     = (const float*)d_in[0];
    p.machines = (const float*)d_in[1];
    p.mask     = (const int*)d_in[2];
    p.jW1 = (const float*)d_in[3];  p.jb1 = (const float*)d_in[4];
    p.jW2 = (const float*)d_in[5];  p.jb2 = (const float*)d_in[6];
    p.mW1 = (const float*)d_in[7];  p.mb1 = (const float*)d_in[8];
    p.mW2 = (const float*)d_in[9];  p.mb2 = (const float*)d_in[10];
    p.aj_Wq = (const float*)d_in[11]; p.aj_bq = (const float*)d_in[12];
    p.aj_Wr = (const float*)d_in[13]; p.aj_V  = (const float*)d_in[14];
    p.am_Wq = (const float*)d_in[15]; p.am_bq = (const float*)d_in[16];
    p.am_Wr = (const float*)d_in[17]; p.am_V  = (const float*)d_in[18];
    p.ja_Wq = (const float*)d_in[19]; p.ja_bq = (const float*)d_in[20];
    p.ja_Wr = (const float*)d_in[21]; p.ja_V  = (const float*)d_in[22];
    p.ma_Wq = (const float*)d_in[23]; p.ma_bq = (const float*)d_in[24];
    p.ma_Wr = (const float*)d_in[25]; p.ma_V  = (const float*)d_in[26];
    p.g1W = (const float*)d_in[27]; p.g1b = (const float*)d_in[28];
    p.g2W = (const float*)d_in[29]; p.g2b = (const float*)d_in[30];
    p.last_j = (const float*)d_in[31];
    p.S = (float*)d_ws;
    p.Ej = (float*)d_ws + E_OFF;
    p.Em = p.Ej + (size_t)GB_J2 * EBLK;
    p.out = (float*)d_out;

    const size_t needed = (E_OFF + (size_t)GB_TOT2 * EBLK) * sizeof(float);
    const bool cache = ws_size >= needed;

    if (cache) {
        k_emb_g1<true><<<GB_TOT2, BLK, 0, stream>>>(p);
        k_combine_g<<<1, BLK, 0, stream>>>(p, 0);
        k_jlogits<true><<<GB_J2, BLK, 0, stream>>>(p);
        k_combine2<<<1, BLK, 0, stream>>>(p);
        k_glimpse2<true><<<GB_TOT2, BLK, 0, stream>>>(p);
        k_combine_g<<<1, BLK, 0, stream>>>(p, 1);
        k_mlogits<true><<<GB_M2, BLK, 0, stream>>>(p);
        k_combine4<<<1, BLK, 0, stream>>>(p);
    } else {
        k_emb_g1<false><<<GB_TOT2, BLK, 0, stream>>>(p);
        k_combine_g<<<1, BLK, 0, stream>>>(p, 0);
        k_jlogits<false><<<GB_J2, BLK, 0, stream>>>(p);
        k_combine2<<<1, BLK, 0, stream>>>(p);
        k_glimpse2<false><<<GB_TOT2, BLK, 0, stream>>>(p);
        k_combine_g<<<1, BLK, 0, stream>>>(p, 1);
        k_mlogits<false><<<GB_M2, BLK, 0, stream>>>(p);
        k_combine4<<<1, BLK, 0, stream>>>(p);
    }
}